// Round 6
// baseline (235.618 us; speedup 1.0000x reference)
//
#include <hip/hip_runtime.h>

#define HW    512
#define OUTW  128
#define NIMG  96                          // 32*3
#define N_HR  ((long long)NIMG*HW*HW)     // 25165824
#define N_LR  ((long long)NIMG*OUTW*OUTW) // 1572864
#define NPART (NIMG*32)                   // one slot per wave (4 out rows each)

// PyTorch bicubic kernel, a = -0.75
__device__ __forceinline__ float cubic075(float x){
    float ax = fabsf(x);
    float ax2 = ax*ax, ax3 = ax2*ax;
    const float A = -0.75f;
    float f1 = (A+2.f)*ax3 - (A+3.f)*ax2 + 1.f;
    float f2 = A*ax3 - 5.f*A*ax2 + 8.f*A*ax - 4.f*A;
    return ax <= 1.f ? f1 : (ax < 2.f ? f2 : 0.f);
}

// scale=4 antialiased window: 16 taps, dist=(k-7.5)/4, normalized.
// Shift-invariant across all output positions (verified absmax=0.0).
__device__ __forceinline__ void get_weights(float w[16]){
    float s = 0.f;
#pragma unroll
    for (int k = 0; k < 16; ++k){
        float d = ((float)k - 7.5f) * 0.25f;
        w[k] = cubic075(d);
        s += w[k];
    }
#pragma unroll
    for (int k = 0; k < 16; ++k) w[k] /= s;
}

// async global->LDS DMA: 64 lanes x 16B = 1KB. LDS dest = wave-uniform base
// + lane*16 (HW); global src per-lane.
__device__ __forceinline__ void gl16(const float* g, float* l){
    __builtin_amdgcn_global_load_lds(
        (const __attribute__((address_space(1))) void*)g,
        (__attribute__((address_space(3))) void*)l,
        16, 0, 0);
}

// R6: per-row pipelining is unwinnable at HIP source (R0 guarded->drains,
// R1 unguarded->sunk, R3 pinned->spilled, R4/R5 counted-vmcnt DMA->still
// ~2400cy/row: every variant serializes one memory round trip per row).
// Amortize instead (m97 discipline): block-cooperative 4-row chunks,
// double-buffered, ONE counted vmcnt(4) + raw s_barrier per chunk, consume
// phase has ZERO VMEM ops (pred AND tgt read from LDS). Worst-case drain
// now costs one latency per 4 rows. Block = 16 out rows; 76 input rows
// staged once (halo 1.19x vs 1.75x). LDS 32KB -> 4 blocks/CU (16 waves,
// VGPR-capped). All weight indices compile-time via wave-uniform switch
// (m = c-4w, 7 cases), h-filter hoisted out of the switch.
__global__ __launch_bounds__(256) void kmain(const float* __restrict__ pred,
                                             const float* __restrict__ tgt,
                                             const float* __restrict__ lr,
                                             double* __restrict__ part){
    __shared__ float bufP[2][4][512];   // 16 KB, double-buffered 4-row chunks
    __shared__ float bufT[2][4][512];   // 16 KB

    // XCD swizzle (bijective, 768%8==0): neutral in R5, kept (free).
    const int logical = ((blockIdx.x & 7) * 96) + (blockIdx.x >> 3);
    const int img  = logical >> 3;
    const int B    = logical & 7;            // block's 16-row band in image
    const int tid  = threadIdx.x;
    const int w    = tid >> 6;               // wave 0..3
    const int l    = tid & 63;
    const int sblk = (B << 6) - 6;           // first (unclamped) input row of block
    const int o0   = (B << 4) + (w << 2);    // wave's first output row

    float wt[16]; get_weights(wt);
    const float* P = pred + (size_t)img * (HW*HW);
    const float* T = tgt  + (size_t)img * (HW*HW);
    const float* L = lr   + (size_t)img * (OUTW*OUTW);

    float acc[4][2] = {{0.f,0.f},{0.f,0.f},{0.f,0.f},{0.f,0.f}};
    float pix_acc = 0.f, lr_acc = 0.f;

    // stage chunk cc (block rows 4cc..4cc+3) into buf[cc&1].
    // wave w, j=0..1: grp=(j<<2)+w in 0..7 -> row=grp>>1, half=grp&1.
    // P rows clamp to [0,511] (replicate border); T rows clamp into the
    // valid pix window [6,70) -- out-of-window stages are garbage-but-safe
    // and never consumed. Exactly 4 DMA instrs per wave per chunk, always.
#define STAGE(cc) do{                                                          \
    _Pragma("unroll")                                                          \
    for (int j = 0; j < 2; ++j){                                               \
        const int grp  = (j<<2) + w;                                           \
        const int row  = grp >> 1;                                             \
        const int half = grp & 1;                                              \
        const int gP   = min(HW-1, max(0, sblk + ((cc)<<2) + row));            \
        gl16(P + (size_t)gP*HW + half*256 + 4*l, &bufP[(cc)&1][row][half*256]);\
        const int bic  = min(69, max(6, ((cc)<<2) + row));                     \
        gl16(T + (size_t)(sblk+bic)*HW + half*256 + 4*l,                       \
             &bufT[(cc)&1][row][half*256]);                                    \
    }                                                                          \
}while(0)

    // v-accumulate one h-filtered row: k = local row index (compile-time)
#define VROW(k, r) do{                                                         \
    if ((k) >= 0  && (k) < 16)  { acc[0][0]+=wt[(k)]   *h[r][0]; acc[0][1]+=wt[(k)]   *h[r][1]; } \
    if ((k) >= 4  && (k) < 20)  { acc[1][0]+=wt[(k)-4] *h[r][0]; acc[1][1]+=wt[(k)-4] *h[r][1]; } \
    if ((k) >= 8  && (k) < 24)  { acc[2][0]+=wt[(k)-8] *h[r][0]; acc[2][1]+=wt[(k)-8] *h[r][1]; } \
    if ((k) >= 12 && (k) < 28)  { acc[3][0]+=wt[(k)-12]*h[r][0]; acc[3][1]+=wt[(k)-12]*h[r][1]; } \
}while(0)

    STAGE(0);                                // prime

#pragma unroll 1
    for (int c = 0; c < 19; ++c){
        STAGE(c+1);                          // prefetch next chunk (c=18 stages safe garbage)
        asm volatile("s_waitcnt vmcnt(4)" ::: "memory");   // chunk c landed; c+1 stays in flight
        __builtin_amdgcn_s_barrier();        // raw barrier: no compiler drain

        // ---- pix: all threads, 2 positions of the 8KB chunk ----
        {
            const int rhi = w >> 1;          // tid>>7, wave-uniform
            const int col = ((w & 1) << 6) + l;   // 0..127
#pragma unroll
            for (int j2 = 0; j2 < 2; ++j2){
                const int row = (j2 << 1) + rhi;
                const int bi  = (c << 2) + row;
                if (bi >= 6 && bi < 70){
                    const float4 pv = *(const float4*)&bufP[c&1][row][col<<2];
                    const float4 tv = *(const float4*)&bufT[c&1][row][col<<2];
                    pix_acc += fabsf(pv.x-tv.x)+fabsf(pv.y-tv.y)
                             + fabsf(pv.z-tv.z)+fabsf(pv.w-tv.w);
                }
            }
        }

        // ---- resize: wave active when its 28-row window covers this chunk ----
        const int m = c - (w << 2);          // chunk phase within window, wave-uniform
        if (m >= 0 && m < 7){
            float h[4][2];
#pragma unroll
            for (int r = 0; r < 4; ++r){
                const float4* pr = (const float4*)&bufP[c&1][r][0];
                const float4 c0 = pr[2*l], c1 = pr[2*l+1];
                const float p0=c0.x,p1v=c0.y,p2v=c0.z,p3=c0.w,
                            p4=c1.x,p5=c1.y,p6=c1.z,p7=c1.w;
                float Lm6 = __shfl_up(p2v,1,64), Lm5 = __shfl_up(p3,1,64),
                      Lm4 = __shfl_up(p4,1,64),  Lm3 = __shfl_up(p5,1,64),
                      Lm2 = __shfl_up(p6,1,64),  Lm1 = __shfl_up(p7,1,64);
                float R8  = __shfl_down(p0,1,64), R9  = __shfl_down(p1v,1,64),
                      R10 = __shfl_down(p2v,1,64),R11 = __shfl_down(p3,1,64),
                      R12 = __shfl_down(p4,1,64), R13 = __shfl_down(p5,1,64);
                if (l == 0){ Lm6=p0; Lm5=p0; Lm4=p0; Lm3=p0; Lm2=p0; Lm1=p0; }
                if (l == 63){ R8=p7; R9=p7; R10=p7; R11=p7; R12=p7; R13=p7; }
                float w20[20] = {Lm6,Lm5,Lm4,Lm3,Lm2,Lm1,p0,p1v,p2v,p3,p4,p5,p6,p7,
                                 R8,R9,R10,R11,R12,R13};
                float h0 = 0.f, h1 = 0.f;
#pragma unroll
                for (int k = 0; k < 16; ++k){ h0 += wt[k]*w20[k]; h1 += wt[k]*w20[k+4]; }
                h[r][0] = h0; h[r][1] = h1;
            }
            switch(m){
                case 0: VROW(0,0);  VROW(1,1);  VROW(2,2);  VROW(3,3);  break;
                case 1: VROW(4,0);  VROW(5,1);  VROW(6,2);  VROW(7,3);  break;
                case 2: VROW(8,0);  VROW(9,1);  VROW(10,2); VROW(11,3); break;
                case 3: VROW(12,0); VROW(13,1); VROW(14,2); VROW(15,3); break;
                case 4: VROW(16,0); VROW(17,1); VROW(18,2); VROW(19,3); break;
                case 5: VROW(20,0); VROW(21,1); VROW(22,2); VROW(23,3); break;
                case 6: VROW(24,0); VROW(25,1); VROW(26,2); VROW(27,3); break;
            }
        }

        __builtin_amdgcn_s_barrier();        // WAR: next iter overwrites buf[c&1]
    }

#undef VROW
#undef STAGE

    // lr term: lane l holds out cols 2l,2l+1 for rows o0..o0+3
#pragma unroll
    for (int q = 0; q < 4; ++q){
        const float2 lv = *(const float2*)(L + (size_t)(o0+q)*OUTW + 2*l);
        lr_acc += fabsf(acc[q][0]-lv.x) + fabsf(acc[q][1]-lv.y);
    }

    // intra-wave reduction, one slot per wave (no atomics, no init needed)
#pragma unroll
    for (int off = 32; off > 0; off >>= 1){
        pix_acc += __shfl_down(pix_acc, off, 64);
        lr_acc  += __shfl_down(lr_acc,  off, 64);
    }
    if (l == 0){
        const int slot = (blockIdx.x << 2) + w;
        part[slot]         = (double)pix_acc;
        part[NPART + slot] = (double)lr_acc;
    }
}

__global__ __launch_bounds__(256) void k3(const double* __restrict__ part,
                                          float* __restrict__ out){
    const int t = threadIdx.x;
    double v1 = 0.0, v2 = 0.0;
    for (int i = t; i < NPART; i += 256){
        v1 += part[i];
        v2 += part[NPART + i];
    }
#pragma unroll
    for (int off = 32; off > 0; off >>= 1){
        v1 += __shfl_down(v1, off, 64);
        v2 += __shfl_down(v2, off, 64);
    }
    __shared__ double s1[4], s2[4];
    const int lane = t & 63, wid = t >> 6;
    if (lane == 0){ s1[wid] = v1; s2[wid] = v2; }
    __syncthreads();
    if (t == 0){
        double S1 = s1[0]+s1[1]+s1[2]+s1[3];
        double S2 = s2[0]+s2[1]+s2[2]+s2[3];
        float pix     = (float)(S1 / (double)N_HR);
        float lr_term = (float)(S2 / (double)N_LR);
        float pair    = 0.f;
        float consist = 1.0f * lr_term + 1.0f * pair;   // LAM_LR, LAM_PAIR
        float total   = pix + 0.1f * consist;           // LAM_CONSIST
        out[0] = total; out[1] = pix; out[2] = consist; out[3] = lr_term; out[4] = pair;
    }
}

extern "C" void kernel_launch(void* const* d_in, const int* in_sizes, int n_in,
                              void* d_out, int out_size, void* d_ws, size_t ws_size,
                              hipStream_t stream){
    const float* pred = (const float*)d_in[0];
    const float* tgt  = (const float*)d_in[1];
    const float* lrr  = (const float*)d_in[2];
    float* out = (float*)d_out;

    double* part = (double*)d_ws;   // 2 * 3072 doubles = 48 KB, every slot written

    kmain<<<NIMG*8, 256, 0, stream>>>(pred, tgt, lrr, part);
    k3<<<1, 256, 0, stream>>>(part, out);
}